// Round 2
// baseline (177.397 us; speedup 1.0000x reference)
//
#include <hip/hip_runtime.h>
#include <hip/hip_bf16.h>

#define NPIX 196608
#define CIN  32
#define COUT 64
#define KNB  9
#define BATCH 4

typedef short short8 __attribute__((ext_vector_type(8)));
typedef float f32x4  __attribute__((ext_vector_type(4)));

static __device__ __forceinline__ unsigned short f2bf(float f) {
    union { float f; unsigned int u; } v; v.f = f;
    unsigned int r = v.u + 0x7FFFu + ((v.u >> 16) & 1u);   // RNE
    return (unsigned short)(r >> 16);
}

// ---------------------------------------------------------------------------
// Kernel 1: pack W (COUT,CIN,K) fp32 -> bf16 in MFMA A-fragment order.
// Wp[((k*4+m)*64 + lane)*8 + j] = bf16( W[o= m*16+(lane&15)][c=(lane>>4)*8+j][k] )
// ---------------------------------------------------------------------------
__global__ __launch_bounds__(256) void wpack_kernel(const float* __restrict__ W,
                                                    unsigned short* __restrict__ Wp) {
    int t = threadIdx.x;
    for (int e = t; e < 18432; e += 256) {
        int j = e & 7;
        int l = (e >> 3) & 63;
        int m = (e >> 9) & 3;
        int k = e >> 11;                       // 0..8
        int o = m * 16 + (l & 15);
        int c = ((l >> 4) << 3) + j;
        Wp[e] = f2bf(W[(o * CIN + c) * KNB + k]);
    }
}

// ---------------------------------------------------------------------------
// Kernel 2: transpose+convert x (B,CIN,NPIX) fp32 -> xT (B,NPIX,CIN) bf16.
// Each block: one batch b, 64-pixel tile. LDS uint = 2 packed bf16 channels.
// ---------------------------------------------------------------------------
__global__ __launch_bounds__(256) void xpose_kernel(const float* __restrict__ x,
                                                    unsigned short* __restrict__ xT) {
    __shared__ unsigned int lds[64][17];
    int t   = threadIdx.x;
    int bid = blockIdx.x;                // 0 .. 4*3072-1
    int b   = bid / 3072;
    int pt  = bid - b * 3072;
    int p0  = pt * 64;

    #pragma unroll
    for (int i = 0; i < 4; ++i) {
        int e  = i * 256 + t;            // 0..1023
        int c2 = e >> 6;                 // channel pair 0..15
        int pp = e & 63;
        const float* xr = x + ((size_t)(b * CIN + 2 * c2)) * NPIX + p0 + pp;
        float lo = xr[0];
        float hi = xr[NPIX];
        lds[pp][c2] = (unsigned int)f2bf(lo) | ((unsigned int)f2bf(hi) << 16);
    }
    __syncthreads();
    #pragma unroll
    for (int i = 0; i < 4; ++i) {
        int e  = i * 256 + t;
        int pp = e >> 4;
        int c2 = e & 15;
        ((unsigned int*)xT)[((size_t)b * NPIX + p0 + pp) * 16 + c2] = lds[pp][c2];
    }
}

// ---------------------------------------------------------------------------
// Kernel 3: main gather + MFMA GEMM.
// Per block: batch b, 256-pixel tile. 4 waves; wave w owns pixels
// [w*64, w*64+64) x all 64 COUT. K-dim = 9 neighbors x 32 channels.
// TR=true : gather 16B fragments from xT (bf16, pixel-major)
// TR=false: fallback, gather 8 strided fp32 scalars from x directly
// ---------------------------------------------------------------------------
template <bool TR>
__global__ __launch_bounds__(256) void conv_kernel(const unsigned short* __restrict__ xT,
                                                   const float* __restrict__ x,
                                                   const int* __restrict__ nbr,
                                                   const unsigned short* __restrict__ Wp,
                                                   const float* __restrict__ bias,
                                                   float* __restrict__ out) {
    __shared__ unsigned short wlds[18432];   // 36 KB
    __shared__ int ilds[2304];               // 9 KB: 256 px * 9 nbrs

    int t   = threadIdx.x;
    int bid = blockIdx.x;                    // 0..3071
    int b   = bid / 768;
    int pt  = bid - b * 768;
    int p0  = pt * 256;

    // stage packed W (linear copy, 16B per thread-iter)
    for (int i = t; i < 2304; i += 256)
        ((uint4*)wlds)[i] = ((const uint4*)Wp)[i];
    // stage neighbor indices (pre-scaled to byte offsets for TR path)
    for (int i = t; i < 2304; i += 256) {
        int idx = nbr[p0 * KNB + i];
        ilds[i] = TR ? (idx << 6) : idx;     // *64B row stride of xT
    }
    __syncthreads();

    int lane = t & 63;
    int wave = t >> 6;
    int r    = lane & 15;
    int q    = lane >> 4;
    int nb   = wave * 64;

    f32x4 acc[4][4] = {};                    // [m-tile][n-frag]

    const char* xb = (const char*)xT + ((size_t)b * NPIX) * 64 + q * 16;

    int prow[4];
    #pragma unroll
    for (int f = 0; f < 4; ++f) prow[f] = (nb + f * 16 + r) * KNB;

    for (int k = 0; k < KNB; ++k) {
        short8 bfrag[4];
        #pragma unroll
        for (int f = 0; f < 4; ++f) {
            int off = ilds[prow[f] + k];
            if (TR) {
                bfrag[f] = *(const short8*)(xb + off);
            } else {
                const float* xc = x + (size_t)(b * CIN + q * 8) * NPIX + off;
                #pragma unroll
                for (int j = 0; j < 8; ++j)
                    bfrag[f][j] = (short)f2bf(xc[(size_t)j * NPIX]);
            }
        }
        short8 afr[4];
        #pragma unroll
        for (int m = 0; m < 4; ++m)
            afr[m] = *(const short8*)&wlds[(((k << 2) | m) * 64 + lane) * 8];
        #pragma unroll
        for (int m = 0; m < 4; ++m)
            #pragma unroll
            for (int f = 0; f < 4; ++f)
                acc[m][f] = __builtin_amdgcn_mfma_f32_16x16x32_bf16(
                                afr[m], bfrag[f], acc[m][f], 0, 0, 0);
    }

    // epilogue: D col = lane&15 -> pixel, row = q*4+reg within 16 -> cout
    float* ob = out + (size_t)b * COUT * NPIX + p0 + nb + r;
    #pragma unroll
    for (int m = 0; m < 4; ++m) {
        f32x4 bv = *(const f32x4*)(bias + m * 16 + q * 4);
        #pragma unroll
        for (int rr = 0; rr < 4; ++rr) {
            float* orow = ob + (size_t)(m * 16 + q * 4 + rr) * NPIX;
            #pragma unroll
            for (int f = 0; f < 4; ++f)
                orow[f * 16] = acc[m][f][rr] + bv[rr];
        }
    }
}

// ---------------------------------------------------------------------------
extern "C" void kernel_launch(void* const* d_in, const int* in_sizes, int n_in,
                              void* d_out, int out_size, void* d_ws, size_t ws_size,
                              hipStream_t stream) {
    const float* x    = (const float*)d_in[0];
    const int*   nbr  = (const int*)d_in[1];
    const float* W    = (const float*)d_in[2];
    const float* bias = (const float*)d_in[3];
    float*       out  = (float*)d_out;

    const size_t wp_bytes = 18432 * sizeof(unsigned short);           // 36,864
    const size_t wp_pad   = (wp_bytes + 255) & ~(size_t)255;
    const size_t xT_bytes = (size_t)BATCH * NPIX * CIN * 2;           // ~50.3 MB

    unsigned short* Wp = (unsigned short*)d_ws;
    unsigned short* xT = (unsigned short*)((char*)d_ws + wp_pad);

    bool full = ws_size >= wp_pad + xT_bytes;

    wpack_kernel<<<1, 256, 0, stream>>>(W, Wp);
    if (full) {
        xpose_kernel<<<BATCH * (NPIX / 64), 256, 0, stream>>>(x, xT);
        conv_kernel<true><<<BATCH * (NPIX / 256), 256, 0, stream>>>(xT, x, nbr, Wp, bias, out);
    } else {
        conv_kernel<false><<<BATCH * (NPIX / 256), 256, 0, stream>>>(xT, x, nbr, Wp, bias, out);
    }
}